// Round 1
// 620.561 us; speedup vs baseline: 1.2403x; 1.2403x over previous
//
#include <hip/hip_runtime.h>

typedef _Float16 f16;
typedef _Float16 f16x8 __attribute__((ext_vector_type(8)));
typedef _Float16 f16x4 __attribute__((ext_vector_type(4)));
typedef float    f32x4 __attribute__((ext_vector_type(4)));

#define N_TOK   100000
#define NPAD    100032         // 3126 * 32 = 1563 * 64
#define NT1     1563           // k1 tiles (64 rows)
#define NT4     1563           // k4 tiles (64 rows)
#define CDIM    512
#define KSTEPS  (NPAD/32)      // 3126
#define K2SPL   128            // split-K partials

// ---------------- workspace layout (bytes) ----------------
#define O_WT     ((size_t)0)                       // w^T fp16 [512][NPAD]
#define SZ_WT    ((size_t)512*NPAD*2)
#define O_YT     (O_WT + SZ_WT)                    // y^T fp16 [64][NPAD]
#define SZ_YT    ((size_t)64*NPAD*2)
#define O_WFR    (O_YT + SZ_YT)                    // frag-linear W+w1 fp16: 16kg*4we*9u*64lane*8 = 589824 B
#define SZ_WFR   ((size_t)16*4*9*64*8*2)
#define O_SPP    (O_WFR + SZ_WFR)                  // s_pre partials [128][32768] f32
#define SZ_SPP   ((size_t)K2SPL*32768*4)
#define O_DPP    (O_SPP + SZ_SPP)                  // d partials [128][512] f32
#define SZ_DPP   ((size_t)K2SPL*512*4)
#define O_SPRE   (O_DPP + SZ_DPP)                  // s_pre [512][64] f32
#define SZ_SPRE  ((size_t)32768*4)
#define O_DSTD   (O_SPRE + SZ_SPRE)                // d [512] f32
#define SZ_DSTD  ((size_t)512*4)
#define O_SOUT   (O_DSTD + SZ_DSTD)                // s_out^T fp16 [8][64dh][64m]

// ---------------- K0: pack W = [w_slice; w1] (576x512) into MFMA-fragment-linear fp16 ----------------
// chunk c = ((kg*4 + we)*9 + u)*64 + lane  holds  Wcat[e][kg*32 + (lane>>4)*8 .. +8]
//   e = (u<8) ? we*128 + u*16 + (lane&15)  :  512 + we*16 + (lane&15)
__global__ void k0_pack(const float* __restrict__ wsf, const float* __restrict__ w1f,
                        f16* __restrict__ wfr) {
    int c = blockIdx.x * 256 + threadIdx.x;      // 36864 chunks total
    int lane = c & 63, g = c >> 6;               // g in 0..575
    int u  = g % 9,  r = g / 9;                  // r in 0..63
    int we = r & 3,  kg = r >> 2;
    int col = lane & 15, quad = lane >> 4;
    int k = kg * 32 + quad * 8;
    const float* src;
    if (u < 8) src = wsf + (size_t)(we*128 + u*16 + col) * CDIM + k;
    else       src = w1f + (size_t)(we*16  + col) * CDIM + k;
    float4 a = *(const float4*)(src);
    float4 b = *(const float4*)(src + 4);
    f16x8 h;
    h[0]=(f16)a.x; h[1]=(f16)a.y; h[2]=(f16)a.z; h[3]=(f16)a.w;
    h[4]=(f16)b.x; h[5]=(f16)b.y; h[6]=(f16)b.z; h[7]=(f16)b.w;
    *(f16x8*)(wfr + (size_t)c * 8) = h;
}

// ---------------- K1: slice GEMM + softmax + y GEMM ----------------
// block = 256 threads (4 waves), one 64-row n-tile per block.
// wave w = e-wave: slice cols w*128..+128 (2 heads) + y cols w*16..+16 (as frag u==8).
// X tile (64n x 32k per k-step) double-buffered in LDS, fp32->f16 staged in regs.
// W fragments loaded straight from frag-linear global (L2-resident, coalesced).
#define XROW 40                                  // padded row (f16): 80 B, 16B-aligned, <=2-way banks
__launch_bounds__(256, 2)
__global__ void k1_slice(const float* __restrict__ x, const float* __restrict__ temperature,
                         const f16* __restrict__ wfr, const float* __restrict__ bsl,
                         f16* __restrict__ wT, f16* __restrict__ yT) {
    __shared__ f16 lX[2][64 * XROW];             // 2 x 5120 B

    const int tid  = threadIdx.x;
    const int wave = tid >> 6;
    const int lane = tid & 63;
    const int quad = lane >> 4;
    const int col  = lane & 15;
    const int n0   = blockIdx.x * 64;

    // staging role: thread -> (row, k-chunk)
    const int srow = tid >> 2, sch = tid & 3;
    int snr = n0 + srow; if (snr > N_TOK - 1) snr = N_TOK - 1;
    const float* sbase = x + (size_t)snr * CDIM + sch * 8;

    // prologue: stage kg=0 into buf 0
    {
        float4 a = *(const float4*)(sbase);
        float4 b = *(const float4*)(sbase + 4);
        f16x8 h;
        h[0]=(f16)a.x; h[1]=(f16)a.y; h[2]=(f16)a.z; h[3]=(f16)a.w;
        h[4]=(f16)b.x; h[5]=(f16)b.y; h[6]=(f16)b.z; h[7]=(f16)b.w;
        *(f16x8*)(&lX[0][srow * XROW + sch * 8]) = h;
    }

    f32x4 acc[4][9];
    #pragma unroll
    for (int nf = 0; nf < 4; ++nf)
        #pragma unroll
        for (int u = 0; u < 9; ++u) acc[nf][u] = f32x4{0.f,0.f,0.f,0.f};

    __syncthreads();

    #pragma unroll 2
    for (int kg = 0; kg < 16; ++kg) {
        // W fragments for this k-step (coalesced, imm-offset; u==8 is the y/w1 frag)
        const f16* wb = wfr + ((size_t)(kg*4 + wave) * 9) * 512 + (size_t)lane * 8;
        f16x8 bf[9];
        #pragma unroll
        for (int u = 0; u < 9; ++u) bf[u] = *(const f16x8*)(wb + u * 512);

        // issue next k-step's x loads early (HBM latency hides under MFMAs)
        float4 xa, xb;
        if (kg < 15) {
            xa = *(const float4*)(sbase + (kg + 1) * 32);
            xb = *(const float4*)(sbase + (kg + 1) * 32 + 4);
        }

        // A fragments from LDS buffer kg&1
        const f16* xbuf = lX[kg & 1];
        f16x8 af[4];
        #pragma unroll
        for (int nf = 0; nf < 4; ++nf)
            af[nf] = *(const f16x8*)(xbuf + (nf*16 + col) * XROW + quad * 8);

        #pragma unroll
        for (int nf = 0; nf < 4; ++nf)
            #pragma unroll
            for (int u = 0; u < 9; ++u)
                acc[nf][u] = __builtin_amdgcn_mfma_f32_16x16x32_f16(af[nf], bf[u], acc[nf][u], 0, 0, 0);

        // write staged x into the other buffer
        if (kg < 15) {
            f16x8 h;
            h[0]=(f16)xa.x; h[1]=(f16)xa.y; h[2]=(f16)xa.z; h[3]=(f16)xa.w;
            h[4]=(f16)xb.x; h[5]=(f16)xb.y; h[6]=(f16)xb.z; h[7]=(f16)xb.w;
            *(f16x8*)(&lX[(kg + 1) & 1][srow * XROW + sch * 8]) = h;
        }
        __syncthreads();
    }

    // ---- bias + temperature ----
    #pragma unroll
    for (int u = 0; u < 8; ++u) {
        float b = bsl[wave*128 + u*16 + col];
        #pragma unroll
        for (int nf = 0; nf < 4; ++nf)
            #pragma unroll
            for (int r = 0; r < 4; ++r) acc[nf][u][r] += b;
    }
    float invt[2];
    #pragma unroll
    for (int hh = 0; hh < 2; ++hh) {
        float tv = temperature[wave*2 + hh];
        tv = fminf(fmaxf(tv, 0.1f), 5.0f);
        invt[hh] = 1.0f / tv;
    }

    // ---- softmax over M=64 per head (16-lane col groups x 4 u-frags), direct stores ----
    #pragma unroll
    for (int nf = 0; nf < 4; ++nf) {
        const int nb = n0 + nf*16 + quad*4;
        #pragma unroll
        for (int hh = 0; hh < 2; ++hh) {
            float mx[4];
            #pragma unroll
            for (int r = 0; r < 4; ++r) {
                float m01 = fmaxf(acc[nf][hh*4+0][r], acc[nf][hh*4+1][r]);
                float m23 = fmaxf(acc[nf][hh*4+2][r], acc[nf][hh*4+3][r]);
                mx[r] = fmaxf(m01, m23);
            }
            #pragma unroll
            for (int d = 1; d < 16; d <<= 1)
                #pragma unroll
                for (int r = 0; r < 4; ++r) mx[r] = fmaxf(mx[r], __shfl_xor(mx[r], d));
            float sm[4] = {0.f, 0.f, 0.f, 0.f};
            #pragma unroll
            for (int uu = 0; uu < 4; ++uu)
                #pragma unroll
                for (int r = 0; r < 4; ++r) {
                    float ev = __expf((acc[nf][hh*4+uu][r] - mx[r]) * invt[hh]);
                    acc[nf][hh*4+uu][r] = ev;
                    sm[r] += ev;
                }
            #pragma unroll
            for (int d = 1; d < 16; d <<= 1)
                #pragma unroll
                for (int r = 0; r < 4; ++r) sm[r] += __shfl_xor(sm[r], d);
            #pragma unroll
            for (int r = 0; r < 4; ++r) sm[r] = 1.0f / sm[r];
            #pragma unroll
            for (int uu = 0; uu < 4; ++uu) {
                f16x4 pk;
                #pragma unroll
                for (int r = 0; r < 4; ++r) {
                    int n = nb + r;
                    float wv = (n < N_TOK) ? acc[nf][hh*4+uu][r] * sm[r] : 0.0f;
                    pk[r] = (f16)wv;
                }
                int e = wave*128 + (hh*4 + uu)*16 + col;
                *(f16x4*)(wT + (size_t)e * NPAD + nb) = pk;
            }
        }
        // y columns (frag u==8): no bias/softmax
        {
            f16x4 pk;
            #pragma unroll
            for (int r = 0; r < 4; ++r) {
                int n = nb + r;
                pk[r] = (n < N_TOK) ? (f16)acc[nf][8][r] : (f16)0.f;
            }
            *(f16x4*)(yT + (size_t)(wave*16 + col) * NPAD + nb) = pk;
        }
    }
}

// ---------------- K2: s_pre = sum_n w[n,e]*y[n,d]  (split-K x e-half, disjoint partials) ----------------
// grid = 256: bid = slot*2 + ehalf; each block: 256e x 64d, ~24 k-steps.
__launch_bounds__(256, 3)
__global__ void k2_spre(const f16* __restrict__ wT, const f16* __restrict__ yT,
                        float* __restrict__ spp, float* __restrict__ dpp) {
    const int tid = threadIdx.x, wave = tid >> 6, lane = tid & 63;
    const int quad = lane >> 4, col = lane & 15;
    const int slot = blockIdx.x >> 1, ehalf = blockIdx.x & 1;
    const int ebase = ehalf * 256 + wave * 64;

    f32x4 acc[4][4];
    float dac[4];
    #pragma unroll
    for (int u = 0; u < 4; ++u) {
        dac[u] = 0.f;
        #pragma unroll
        for (int v = 0; v < 4; ++v) acc[u][v] = f32x4{0.f,0.f,0.f,0.f};
    }
    for (int ks = slot; ks < KSTEPS; ks += K2SPL) {
        int nb = ks*32 + quad*8;
        f16x8 bf[4];
        #pragma unroll
        for (int v = 0; v < 4; ++v)
            bf[v] = *(const f16x8*)(yT + (size_t)(v*16 + col)*NPAD + nb);
        #pragma unroll
        for (int u = 0; u < 4; ++u) {
            f16x8 af = *(const f16x8*)(wT + (size_t)(ebase + u*16 + col)*NPAD + nb);
            #pragma unroll
            for (int v = 0; v < 4; ++v)
                acc[u][v] = __builtin_amdgcn_mfma_f32_16x16x32_f16(af, bf[v], acc[u][v], 0, 0, 0);
            float s = 0.f;
            #pragma unroll
            for (int j = 0; j < 8; ++j) s += (float)af[j];
            dac[u] += s;
        }
    }
    #pragma unroll
    for (int u = 0; u < 4; ++u) {
        dac[u] += __shfl_xor(dac[u], 16);
        dac[u] += __shfl_xor(dac[u], 32);
    }
    if (quad == 0) {
        #pragma unroll
        for (int u = 0; u < 4; ++u)
            dpp[slot*512 + ebase + u*16 + col] = dac[u];
    }
    // partial layout: [slot][ehalf*16384 + ((wave*4+u)*4+v)*256 + lane*4]
    float* dst = spp + (size_t)slot * 32768 + (size_t)ehalf * 16384;
    #pragma unroll
    for (int u = 0; u < 4; ++u)
        #pragma unroll
        for (int v = 0; v < 4; ++v)
            *(f32x4*)(dst + (size_t)((wave*4 + u)*4 + v)*256 + (size_t)lane*4) = acc[u][v];
}

// ---------------- K2r: reduce partials, de-swizzle frag order ----------------
__global__ void k2r_reduce(const float* __restrict__ spp, const float* __restrict__ dpp,
                           float* __restrict__ spre, float* __restrict__ dstd) {
    int i = blockIdx.x*256 + threadIdx.x;   // 32768
    float s = 0.f;
    for (int p = 0; p < K2SPL; ++p) s += spp[(size_t)p*32768 + i];
    int r = i & 3, L = (i >> 2) & 63, v = (i >> 8) & 3, t = (i >> 10) & 15, eh = i >> 14;
    int e = eh*256 + (t >> 2)*64 + (t & 3)*16 + (L >> 4)*4 + r;
    int d = v*16 + (L & 15);
    spre[e*64 + d] = s;
    if (i < 512) {
        float tt = 0.f;
        for (int p = 0; p < K2SPL; ++p) tt += dpp[p*512 + i];
        dstd[i] = tt;
    }
}

// ---------------- K3: per-head middle block (exact fp32, all-LDS) ----------------
__global__ void k3_attn(const float* __restrict__ spre, const float* __restrict__ dstd,
                        const float* __restrict__ b1, const float* __restrict__ wq,
                        const float* __restrict__ wk, const float* __restrict__ wv,
                        const float* __restrict__ w3, const float* __restrict__ b3,
                        f16* __restrict__ sout) {
    __shared__ float wa[64][65], wb[64][65], wc[64][65];   // wq,wk,wv; wa reused for w3
    __shared__ float ss[64][65], qq[64][65], kk[64][65], vv[64][65], sc[64][65];
    const int h = blockIdx.x, tid = threadIdx.x;

    // stage weights (coalesced) + s
    for (int i = tid; i < 4096; i += 256) {
        int r = i >> 6, c = i & 63;
        wa[r][c] = wq[i];
        wb[r][c] = wk[i];
        wc[r][c] = wv[i];
        ss[r][c] = spre[h*4096 + i] / (dstd[h*64 + r] + 1e-5f) + b1[c];
    }
    __syncthreads();

    // q,k,v: lane-varying index e hits padded rows (bank-conflict-free)
    #pragma unroll
    for (int it = 0; it < 16; ++it) {
        int m = it*4 + (tid >> 6), e = tid & 63;
        float aq = 0.f, ak = 0.f, av = 0.f;
        #pragma unroll 8
        for (int d = 0; d < 64; ++d) {
            float sv = ss[m][d];                // broadcast
            aq += sv * wa[e][d];
            ak += sv * wb[e][d];
            av += sv * wc[e][d];
        }
        qq[m][e] = aq; kk[m][e] = ak; vv[m][e] = av;
    }
    __syncthreads();

    // scores; also stage w3 into wa (wa dead after qkv)
    for (int i = tid; i < 4096; i += 256) wa[i >> 6][i & 63] = w3[i];
    #pragma unroll
    for (int it = 0; it < 16; ++it) {
        int m = it*4 + (tid >> 6), l = tid & 63;
        float a = 0.f;
        #pragma unroll 8
        for (int e = 0; e < 64; ++e) a += qq[m][e] * kk[l][e];
        sc[m][l] = a * 0.125f;
    }
    __syncthreads();

    // softmax rows
    if (tid < 64) {
        int m = tid;
        float mx = -1e30f;
        #pragma unroll 8
        for (int l = 0; l < 64; ++l) mx = fmaxf(mx, sc[m][l]);
        float sm = 0.f;
        #pragma unroll 8
        for (int l = 0; l < 64; ++l) { float ev = __expf(sc[m][l] - mx); sc[m][l] = ev; sm += ev; }
        float rs = 1.0f / sm;
        #pragma unroll 8
        for (int l = 0; l < 64; ++l) sc[m][l] *= rs;
    }
    __syncthreads();

    // s_att -> ss (ss dead after qkv)
    #pragma unroll
    for (int it = 0; it < 16; ++it) {
        int m = it*4 + (tid >> 6), e = tid & 63;
        float a = 0.f;
        #pragma unroll 8
        for (int l = 0; l < 64; ++l) a += sc[m][l] * vv[l][e];   // sc broadcast
        ss[m][e] = a;
    }
    __syncthreads();

    // s_out^T: lanes vary m -> contiguous store; wa[d][e] broadcast
    #pragma unroll
    for (int it = 0; it < 16; ++it) {
        int d = it*4 + (tid >> 6), m = tid & 63;
        float a = b3[d];
        #pragma unroll 8
        for (int e = 0; e < 64; ++e) a += ss[m][e] * wa[d][e];
        sout[(h*64 + d)*64 + m] = (f16)a;
    }
}

// ---------------- K4: deslice x_out = w @ s_out ----------------
__launch_bounds__(256, 2)
__global__ void k4_deslice(const f16* __restrict__ wT, const f16* __restrict__ sout,
                           float* __restrict__ out) {
    __shared__ f16 ldsW[512*68];
    const int tid = threadIdx.x, wave = tid >> 6, lane = tid & 63;
    const int quad = lane >> 4, col = lane & 15;
    const int n0 = blockIdx.x * 64;

    #pragma unroll
    for (int i = 0; i < 32; ++i) {
        int id = tid + i*256;               // 8192 = 512 rows x 16 chunks
        int e = id >> 4, p = id & 15;
        f16x4 v = *(const f16x4*)(wT + (size_t)e*NPAD + n0 + p*4);
        *(f16x4*)(ldsW + (size_t)e*68 + p*4) = v;
    }
    __syncthreads();

    f32x4 acc[2][4][4];
    #pragma unroll
    for (int hh = 0; hh < 2; ++hh)
        #pragma unroll
        for (int t = 0; t < 4; ++t)
            #pragma unroll
            for (int v = 0; v < 4; ++v) acc[hh][t][v] = f32x4{0.f,0.f,0.f,0.f};

    #pragma unroll
    for (int hh = 0; hh < 2; ++hh) {
        int h = wave*2 + hh;
        #pragma unroll
        for (int ks = 0; ks < 2; ++ks) {
            f16x8 af[4];
            #pragma unroll
            for (int t = 0; t < 4; ++t) {
                f16x8 a;
                #pragma unroll
                for (int j = 0; j < 8; ++j)
                    a[j] = ldsW[(size_t)(h*64 + ks*32 + quad*8 + j)*68 + t*16 + col];
                af[t] = a;
            }
            #pragma unroll
            for (int v = 0; v < 4; ++v) {
                f16x8 bf = *(const f16x8*)(sout + (size_t)(h*64 + v*16 + col)*64 + ks*32 + quad*8);
                #pragma unroll
                for (int t = 0; t < 4; ++t)
                    acc[hh][t][v] = __builtin_amdgcn_mfma_f32_16x16x32_f16(af[t], bf, acc[hh][t][v], 0, 0, 0);
            }
        }
    }

    #pragma unroll
    for (int hh = 0; hh < 2; ++hh) {
        int h = wave*2 + hh;
        #pragma unroll
        for (int t = 0; t < 4; ++t)
            #pragma unroll
            for (int v = 0; v < 4; ++v)
                #pragma unroll
                for (int r = 0; r < 4; ++r) {
                    int n = n0 + t*16 + quad*4 + r;
                    if (n < N_TOK)
                        out[(size_t)n*512 + h*64 + v*16 + col] = acc[hh][t][v][r];
                }
    }
}

// ---------------- launcher ----------------
extern "C" void kernel_launch(void* const* d_in, const int* in_sizes, int n_in,
                              void* d_out, int out_size, void* d_ws, size_t ws_size,
                              hipStream_t stream) {
    const float* x           = (const float*)d_in[0];
    const float* temperature = (const float*)d_in[1];
    const float* w_slice     = (const float*)d_in[2];
    const float* b_slice     = (const float*)d_in[3];
    const float* w1          = (const float*)d_in[4];
    const float* b1          = (const float*)d_in[5];
    const float* wq          = (const float*)d_in[6];
    const float* wk          = (const float*)d_in[7];
    const float* wv          = (const float*)d_in[8];
    const float* w3          = (const float*)d_in[9];
    const float* b3          = (const float*)d_in[10];
    float* out = (float*)d_out;
    char*  ws  = (char*)d_ws;

    f16*   wT    = (f16*)(ws + O_WT);
    f16*   yT    = (f16*)(ws + O_YT);
    f16*   wfr   = (f16*)(ws + O_WFR);
    float* spp   = (float*)(ws + O_SPP);
    float* dpp   = (float*)(ws + O_DPP);
    float* spre  = (float*)(ws + O_SPRE);
    float* dstd  = (float*)(ws + O_DSTD);
    f16*   sout  = (f16*)(ws + O_SOUT);

    k0_pack<<<144, 256, 0, stream>>>(w_slice, w1, wfr);
    k1_slice<<<NT1, 256, 0, stream>>>(x, temperature, wfr, b_slice, wT, yT);
    k2_spre<<<K2SPL*2, 256, 0, stream>>>(wT, yT, spp, dpp);
    k2r_reduce<<<128, 256, 0, stream>>>(spp, dpp, spre, dstd);
    k3_attn<<<8, 256, 0, stream>>>(spre, dstd, b1, wq, wk, wv, w3, b3, sout);
    k4_deslice<<<NT4, 256, 0, stream>>>(wT, sout, out);
}